// Round 13
// baseline (344.818 us; speedup 1.0000x reference)
//
#include <hip/hip_runtime.h>
#include <math.h>

#define C_ 32
#define D_ 48
#define H_ 128
#define W_ 160
#define HW_ (H_*W_)
#define DHW_ (D_*HW_)

// Constant-address-space pointer: forces AMDGPU uniform+invariant treatment
// -> s_load via scalar K$ (weights land in SGPRs, not VGPRs, no LDS pipe).
typedef const float __attribute__((address_space(4))) kfloat;

// ---------------- small matrix helpers (device, used by 1-thread setup) ----

__device__ __forceinline__ void combine4(const float* p, float* out) {
    #pragma unroll
    for (int i = 0; i < 16; ++i) out[i] = p[i];
    #pragma unroll
    for (int i = 0; i < 3; ++i) {
        #pragma unroll
        for (int j = 0; j < 4; ++j) {
            float s = 0.f;
            #pragma unroll
            for (int k = 0; k < 3; ++k) s += p[16 + i*4 + k] * p[k*4 + j];
            out[i*4 + j] = s;
        }
    }
}

__device__ void inv4(const float* A, float* out) {
    float M[4][8];
    for (int i = 0; i < 4; ++i)
        for (int j = 0; j < 4; ++j) {
            M[i][j] = A[i*4 + j];
            M[i][4 + j] = (i == j) ? 1.f : 0.f;
        }
    for (int c = 0; c < 4; ++c) {
        int piv = c; float best = fabsf(M[c][c]);
        for (int r = c + 1; r < 4; ++r) {
            float a = fabsf(M[r][c]);
            if (a > best) { best = a; piv = r; }
        }
        if (piv != c)
            for (int j = 0; j < 8; ++j) { float t = M[c][j]; M[c][j] = M[piv][j]; M[piv][j] = t; }
        float ip = 1.f / M[c][c];
        for (int j = 0; j < 8; ++j) M[c][j] *= ip;
        for (int r = 0; r < 4; ++r) if (r != c) {
            float f = M[r][c];
            for (int j = 0; j < 8; ++j) M[r][j] -= f * M[c][j];
        }
    }
    for (int i = 0; i < 4; ++i)
        for (int j = 0; j < 4; ++j) out[i*4 + j] = M[i][4 + j];
}

__device__ __forceinline__ void matmul4(const float* A, const float* B, float* Cm) {
    #pragma unroll
    for (int i = 0; i < 4; ++i)
        #pragma unroll
        for (int j = 0; j < 4; ++j) {
            float s = 0.f;
            #pragma unroll
            for (int k = 0; k < 4; ++k) s += A[i*4 + k] * B[k*4 + j];
            Cm[i*4 + j] = s;
        }
}

__global__ void proj_setup_kernel(const float* __restrict__ refp,
                                  const float* __restrict__ sp1,
                                  const float* __restrict__ sp2,
                                  float* __restrict__ proj_out) {
    if (threadIdx.x != 0 || blockIdx.x != 0) return;
    float rc[16], s1[16], s2[16], ri[16], p[16];
    combine4(refp, rc);
    combine4(sp1, s1);
    combine4(sp2, s2);
    inv4(rc, ri);
    for (int v = 0; v < 2; ++v) {
        matmul4(v == 0 ? s1 : s2, ri, p);
        for (int i = 0; i < 3; ++i)
            for (int j = 0; j < 3; ++j) proj_out[v*12 + i*3 + j] = p[i*4 + j];
        for (int i = 0; i < 3; ++i) proj_out[v*12 + 9 + i] = p[i*4 + 3];
    }
}

// ---------------- warp + variance -----------------------------------------

__global__ __launch_bounds__(256) void variance_kernel(
        const float* __restrict__ ref,
        const float* __restrict__ s1g,
        const float* __restrict__ s2g,
        const float* __restrict__ depthv,
        const float* __restrict__ proj,
        float* __restrict__ var) {
    int idx = blockIdx.x * 256 + threadIdx.x;   // < DHW_
    int x = idx % W_;
    int t = idx / W_;
    int y = t % H_;
    float depth = depthv[idx];
    float fx = (float)x, fy = (float)y;

    int off[2][4];
    float wt[2][4];
    #pragma unroll
    for (int v = 0; v < 2; ++v) {
        const float* P = proj + v*12;
        float rx = P[0]*fx + P[1]*fy + P[2];
        float ry = P[3]*fx + P[4]*fy + P[5];
        float rz = P[6]*fx + P[7]*fy + P[8];
        float X = rx*depth + P[9];
        float Y = ry*depth + P[10];
        float Z = rz*depth + P[11];
        float z = (fabsf(Z) < 1e-6f) ? 1e-6f : Z;
        float px = X / z;
        float py = Y / z;
        float x0f = floorf(px), y0f = floorf(py);
        float wx = px - x0f, wy = py - y0f;
        #pragma unroll
        for (int k = 0; k < 4; ++k) {
            float xi = x0f + (float)(k & 1);
            float yi = y0f + (float)(k >> 1);
            bool valid = (xi >= 0.f) && (xi <= (float)(W_-1)) &&
                         (yi >= 0.f) && (yi <= (float)(H_-1));
            int xc = (int)fminf(fmaxf(xi, 0.f), (float)(W_-1));
            int yc = (int)fminf(fmaxf(yi, 0.f), (float)(H_-1));
            off[v][k] = yc * W_ + xc;
            float w = ((k & 1) ? wx : 1.f - wx) * ((k >> 1) ? wy : 1.f - wy);
            wt[v][k] = valid ? w : 0.f;
        }
    }

    int pix = y*W_ + x;
    size_t obase = (size_t)idx;
    const float inv3 = 1.f / 3.f;
    #pragma unroll 4
    for (int c = 0; c < C_; ++c) {
        const float* p1 = s1g + c*HW_;
        const float* p2 = s2g + c*HW_;
        float r = ref[c*HW_ + pix];
        float wv1 = wt[0][0]*p1[off[0][0]] + wt[0][1]*p1[off[0][1]]
                  + wt[0][2]*p1[off[0][2]] + wt[0][3]*p1[off[0][3]];
        float wv2 = wt[1][0]*p2[off[1][0]] + wt[1][1]*p2[off[1][1]]
                  + wt[1][2]*p2[off[1][2]] + wt[1][3]*p2[off[1][3]];
        float s = r + wv1 + wv2;
        float q = r*r + wv1*wv1 + wv2*wv2;
        float m = s * inv3;
        var[(size_t)c*DHW_ + obase] = q*inv3 - m*m;
    }
}

// ---------------- 3D conv, SAME padding, NCDHW ----------------------------
// R12 post-mortem: TD=8 didn't deliver because (a) 480-block grid = 5.6
// waves/CU (occupancy 17.5%) can't saturate the LDS pipe, and (b) 648 of
// 1170 LDS cyc/ic/wave were ds_read_b128 WEIGHT broadcasts -- every wave
// re-reading the same values. R12 change: weights via address_space(4)
// pointer -> s_load through scalar K$ into SGPRs (uniform+invariant by
// construction; fixes R3 where the compiler chose per-lane VMEM). LDS pipe
// now carries values only (522 cyc/ic/wave = 52us chip); FMA floor (86us)
// becomes binding. wlds removed entirely: LDS 41.5 -> 13.8 KB.
// Kept: TD=8, runtime-ij loop (live-set bound), T14 register prefetch,
// branch-free hoisted staging, [d][y][x] tile (stride-1 x, conflict-free).

template<int IC, int OC, int TD, bool RELU>
__global__ __launch_bounds__(256) void conv3d_kernel(
        const float* __restrict__ in,
        const float* __restrict__ wgt,   // (OC, IC, 3,3,3) original layout
        const float* __restrict__ bias,  // (OC)
        float* __restrict__ out) {
    const int TW = 32, TH = 8;
    const int TILE = (TD+2)*(TH+2)*(TW+2);          // TD=8: 10*10*34 = 3400
    const int PLANE = (TH+2)*(TW+2);                // 340
    const int LOADS = (TILE + 255) / 256;           // TD=8: 14
    const int tx = threadIdx.x & 31;
    const int ty = threadIdx.x >> 5;
    const int x0 = blockIdx.x * TW;
    const int y0 = blockIdx.y * TH;
    const int d0 = blockIdx.z * TD;

    __shared__ __attribute__((aligned(16))) float tile[TILE];

    // scalar-path weight pointer (addrspace 4 = constant)
    kfloat* wk = (kfloat*)(unsigned long long)wgt;

    // ---- precompute staging slots (ic-invariant, branch-free) ----
    int   goff[LOADS];
    float gmsk[LOADS];
    #pragma unroll
    for (int k = 0; k < LOADS; ++k) {
        int s = threadIdx.x + k*256;
        int lx = s % (TW+2);
        int lt = s / (TW+2);
        int ly = lt % (TH+2);
        int ld = lt / (TH+2);
        int gx = x0 + lx - 1;
        int gy = y0 + ly - 1;
        int gd = d0 + ld - 1;
        bool ok = (s < TILE) && gx >= 0 && gx < W_ && gy >= 0 && gy < H_
                             && gd >= 0 && gd < D_;
        goff[k] = ok ? (gd*HW_ + gy*W_ + gx) : 0;
        gmsk[k] = ok ? 1.f : 0.f;
    }

    float acc[TD][OC];
    #pragma unroll
    for (int od = 0; od < TD; ++od)
        #pragma unroll
        for (int oc = 0; oc < OC; ++oc) acc[od][oc] = bias[oc];

    // prologue: prefetch ic=0 staging values into registers
    float pre[LOADS];
    #pragma unroll
    for (int k = 0; k < LOADS; ++k) pre[k] = in[goff[k]] * gmsk[k];

    for (int ic = 0; ic < IC; ++ic) {
        __syncthreads();               // previous compute done reading tile
        #pragma unroll
        for (int k = 0; k < LOADS; ++k) {
            int s = threadIdx.x + k*256;
            if (s < TILE) tile[s] = pre[k];
        }
        __syncthreads();               // tile ready

        // issue next-ic staging loads NOW; first use is next-iter ds_write,
        // so the latency hides under this iteration's 9-tap FMA phase.
        if (ic + 1 < IC) {
            const float* incn = in + (size_t)(ic + 1) * DHW_;
            #pragma unroll
            for (int k = 0; k < LOADS; ++k) pre[k] = incn[goff[k]] * gmsk[k];
        }

        int lbase = ty*(TW+2) + tx;     // (i=0, j=0) tap address
        int jj = 0;
        #pragma unroll 1
        for (int ij = 0; ij < 9; ++ij) {
            float vals[TD+2];
            #pragma unroll
            for (int p = 0; p < TD+2; ++p)
                vals[p] = tile[p*PLANE + lbase];
            // weights: uniform base (ic,ij) + compile-time (oc,kd) offsets
            // -> s_load s[..], K$-cached, SGPR operand into v_fmac
            kfloat* wp = wk + ic*27 + ij;
            #pragma unroll
            for (int kd = 0; kd < 3; ++kd)
                #pragma unroll
                for (int od = 0; od < TD; ++od) {
                    float v = vals[od + kd];
                    #pragma unroll
                    for (int oc = 0; oc < OC; ++oc)
                        acc[od][oc] = fmaf(wp[oc*IC*27 + kd*9], v, acc[od][oc]);
                }
            // advance tap: j=0,1,2 then next i row
            if (jj == 2) { jj = 0; lbase += (TW+2) - 2; }
            else         { ++jj; ++lbase; }
        }
    }

    #pragma unroll
    for (int od = 0; od < TD; ++od) {
        int obase = (d0 + od)*HW_ + (y0 + ty)*W_ + (x0 + tx);
        #pragma unroll
        for (int oc = 0; oc < OC; ++oc) {
            float r = acc[od][oc];
            if (RELU) r = fmaxf(r, 0.f);
            out[(size_t)oc*DHW_ + obase] = r;
        }
    }
}

// ---------------- softmax over D ------------------------------------------

__global__ __launch_bounds__(256) void softmax_kernel(
        const float* __restrict__ logits, float* __restrict__ out) {
    int pix = blockIdx.x * 256 + threadIdx.x;   // < HW_
    float v[D_];
    float m = -1e30f;
    #pragma unroll
    for (int d = 0; d < D_; ++d) {
        v[d] = logits[d*HW_ + pix];
        m = fmaxf(m, v[d]);
    }
    float s = 0.f;
    #pragma unroll
    for (int d = 0; d < D_; ++d) {
        v[d] = expf(v[d] - m);
        s += v[d];
    }
    float is = 1.f / s;
    #pragma unroll
    for (int d = 0; d < D_; ++d) out[d*HW_ + pix] = v[d] * is;
}

// ---------------- launch ---------------------------------------------------
// ws layout FROZEN (passed rounds 1, 4, 6, 8, 9, 12):
//   proj @ ws+0 (256 B) | var: 32*DHW f32 (126 MB) | hid: 8*DHW f32 (31.5 MB)
// Total 157,286,656 B. Do NOT add ws allocations (round-3 overflow lesson).

extern "C" void kernel_launch(void* const* d_in, const int* in_sizes, int n_in,
                              void* d_out, int out_size, void* d_ws, size_t ws_size,
                              hipStream_t stream) {
    const float* ref_fea = (const float*)d_in[0];
    const float* src1    = (const float*)d_in[1];
    const float* src2    = (const float*)d_in[2];
    const float* ref_prj = (const float*)d_in[3];
    const float* src_pr1 = (const float*)d_in[4];
    const float* src_pr2 = (const float*)d_in[5];
    const float* depth   = (const float*)d_in[6];
    const float* w1      = (const float*)d_in[7];
    const float* b1      = (const float*)d_in[8];
    const float* w2      = (const float*)d_in[9];
    const float* b2      = (const float*)d_in[10];
    float* out = (float*)d_out;

    char* ws = (char*)d_ws;
    float* proj   = (float*)ws;                                         // 24 f
    float* var    = (float*)(ws + 256);                                 // 126 MB
    float* hid    = (float*)(ws + 256 + (size_t)C_*DHW_*sizeof(float)); // 31.5 MB
    float* logits = var;  // variance region dead after conv1 -> reuse

    proj_setup_kernel<<<1, 64, 0, stream>>>(ref_prj, src_pr1, src_pr2, proj);

    variance_kernel<<<DHW_/256, 256, 0, stream>>>(ref_fea, src1, src2, depth, proj, var);

    dim3 cgrid(W_/32, H_/8, D_/8);   // 5 x 16 x 6 = 480 blocks
    conv3d_kernel<32, 8, 8, true ><<<cgrid, 256, 0, stream>>>(var, w1, b1, hid);
    conv3d_kernel< 8, 1, 8, false><<<cgrid, 256, 0, stream>>>(hid, w2, b2, logits);

    softmax_kernel<<<HW_/256, 256, 0, stream>>>(logits, out);
}

// Round 15
// 340.539 us; speedup vs baseline: 1.0126x; 1.0126x over previous
//
#include <hip/hip_runtime.h>
#include <math.h>

#define C_ 32
#define D_ 48
#define H_ 128
#define W_ 160
#define HW_ (H_*W_)
#define DHW_ (D_*HW_)

// Constant-address-space pointer: forces AMDGPU uniform+invariant treatment
// -> s_load via scalar K$ (weights land in SGPRs, not VGPRs, no LDS pipe).
typedef const float __attribute__((address_space(4))) kfloat;

// ---------------- small matrix helpers (device, used by 1-thread setup) ----

__device__ __forceinline__ void combine4(const float* p, float* out) {
    #pragma unroll
    for (int i = 0; i < 16; ++i) out[i] = p[i];
    #pragma unroll
    for (int i = 0; i < 3; ++i) {
        #pragma unroll
        for (int j = 0; j < 4; ++j) {
            float s = 0.f;
            #pragma unroll
            for (int k = 0; k < 3; ++k) s += p[16 + i*4 + k] * p[k*4 + j];
            out[i*4 + j] = s;
        }
    }
}

__device__ void inv4(const float* A, float* out) {
    float M[4][8];
    for (int i = 0; i < 4; ++i)
        for (int j = 0; j < 4; ++j) {
            M[i][j] = A[i*4 + j];
            M[i][4 + j] = (i == j) ? 1.f : 0.f;
        }
    for (int c = 0; c < 4; ++c) {
        int piv = c; float best = fabsf(M[c][c]);
        for (int r = c + 1; r < 4; ++r) {
            float a = fabsf(M[r][c]);
            if (a > best) { best = a; piv = r; }
        }
        if (piv != c)
            for (int j = 0; j < 8; ++j) { float t = M[c][j]; M[c][j] = M[piv][j]; M[piv][j] = t; }
        float ip = 1.f / M[c][c];
        for (int j = 0; j < 8; ++j) M[c][j] *= ip;
        for (int r = 0; r < 4; ++r) if (r != c) {
            float f = M[r][c];
            for (int j = 0; j < 8; ++j) M[r][j] -= f * M[c][j];
        }
    }
    for (int i = 0; i < 4; ++i)
        for (int j = 0; j < 4; ++j) out[i*4 + j] = M[i][4 + j];
}

__device__ __forceinline__ void matmul4(const float* A, const float* B, float* Cm) {
    #pragma unroll
    for (int i = 0; i < 4; ++i)
        #pragma unroll
        for (int j = 0; j < 4; ++j) {
            float s = 0.f;
            #pragma unroll
            for (int k = 0; k < 4; ++k) s += A[i*4 + k] * B[k*4 + j];
            Cm[i*4 + j] = s;
        }
}

__global__ void proj_setup_kernel(const float* __restrict__ refp,
                                  const float* __restrict__ sp1,
                                  const float* __restrict__ sp2,
                                  float* __restrict__ proj_out) {
    if (threadIdx.x != 0 || blockIdx.x != 0) return;
    float rc[16], s1[16], s2[16], ri[16], p[16];
    combine4(refp, rc);
    combine4(sp1, s1);
    combine4(sp2, s2);
    inv4(rc, ri);
    for (int v = 0; v < 2; ++v) {
        matmul4(v == 0 ? s1 : s2, ri, p);
        for (int i = 0; i < 3; ++i)
            for (int j = 0; j < 3; ++j) proj_out[v*12 + i*3 + j] = p[i*4 + j];
        for (int i = 0; i < 3; ++i) proj_out[v*12 + 9 + i] = p[i*4 + 3];
    }
}

// ---------------- warp + variance -----------------------------------------

__global__ __launch_bounds__(256) void variance_kernel(
        const float* __restrict__ ref,
        const float* __restrict__ s1g,
        const float* __restrict__ s2g,
        const float* __restrict__ depthv,
        const float* __restrict__ proj,
        float* __restrict__ var) {
    int idx = blockIdx.x * 256 + threadIdx.x;   // < DHW_
    int x = idx % W_;
    int t = idx / W_;
    int y = t % H_;
    float depth = depthv[idx];
    float fx = (float)x, fy = (float)y;

    int off[2][4];
    float wt[2][4];
    #pragma unroll
    for (int v = 0; v < 2; ++v) {
        const float* P = proj + v*12;
        float rx = P[0]*fx + P[1]*fy + P[2];
        float ry = P[3]*fx + P[4]*fy + P[5];
        float rz = P[6]*fx + P[7]*fy + P[8];
        float X = rx*depth + P[9];
        float Y = ry*depth + P[10];
        float Z = rz*depth + P[11];
        float z = (fabsf(Z) < 1e-6f) ? 1e-6f : Z;
        float px = X / z;
        float py = Y / z;
        float x0f = floorf(px), y0f = floorf(py);
        float wx = px - x0f, wy = py - y0f;
        #pragma unroll
        for (int k = 0; k < 4; ++k) {
            float xi = x0f + (float)(k & 1);
            float yi = y0f + (float)(k >> 1);
            bool valid = (xi >= 0.f) && (xi <= (float)(W_-1)) &&
                         (yi >= 0.f) && (yi <= (float)(H_-1));
            int xc = (int)fminf(fmaxf(xi, 0.f), (float)(W_-1));
            int yc = (int)fminf(fmaxf(yi, 0.f), (float)(H_-1));
            off[v][k] = yc * W_ + xc;
            float w = ((k & 1) ? wx : 1.f - wx) * ((k >> 1) ? wy : 1.f - wy);
            wt[v][k] = valid ? w : 0.f;
        }
    }

    int pix = y*W_ + x;
    size_t obase = (size_t)idx;
    const float inv3 = 1.f / 3.f;
    #pragma unroll 4
    for (int c = 0; c < C_; ++c) {
        const float* p1 = s1g + c*HW_;
        const float* p2 = s2g + c*HW_;
        float r = ref[c*HW_ + pix];
        float wv1 = wt[0][0]*p1[off[0][0]] + wt[0][1]*p1[off[0][1]]
                  + wt[0][2]*p1[off[0][2]] + wt[0][3]*p1[off[0][3]];
        float wv2 = wt[1][0]*p2[off[1][0]] + wt[1][1]*p2[off[1][1]]
                  + wt[1][2]*p2[off[1][2]] + wt[1][3]*p2[off[1][3]];
        float s = r + wv1 + wv2;
        float q = r*r + wv1*wv1 + wv2*wv2;
        float m = s * inv3;
        var[(size_t)c*DHW_ + obase] = q*inv3 - m*m;
    }
}

// ---------------- 3D conv, SAME padding, NCDHW ----------------------------
// R13 post-mortem: s_load weights landed (SGPR 64, LDS 13.8KB) but TD=8's
// 1.4 waves/SIMD exposed every coarse lgkmcnt wait (s_load and ds_read
// SHARE the counter) -> VALUBusy 50%, 198us. This round: combine s_load
// weights with TD=4's 960-block grid (3.75 waves/SIMD). Per-CU per-ic:
// FMA 1728 cyc/SIMD > LDS values-only 1252 cyc -> FMA-bound for the first
// time; TLP covers the lgkm waits. conv2 stays TD=8 (staging-dominated).
// Kept: runtime-ij loop (live-set bound), T14 register prefetch,
// branch-free hoisted staging, [d][y][x] tile (stride-1 x, conflict-free).

template<int IC, int OC, int TD, bool RELU>
__global__ __launch_bounds__(256) void conv3d_kernel(
        const float* __restrict__ in,
        const float* __restrict__ wgt,   // (OC, IC, 3,3,3) original layout
        const float* __restrict__ bias,  // (OC)
        float* __restrict__ out) {
    const int TW = 32, TH = 8;
    const int TILE = (TD+2)*(TH+2)*(TW+2);          // TD=4: 2040, TD=8: 3400
    const int PLANE = (TH+2)*(TW+2);                // 340
    const int LOADS = (TILE + 255) / 256;           // TD=4: 8, TD=8: 14
    const int tx = threadIdx.x & 31;
    const int ty = threadIdx.x >> 5;
    const int x0 = blockIdx.x * TW;
    const int y0 = blockIdx.y * TH;
    const int d0 = blockIdx.z * TD;

    __shared__ __attribute__((aligned(16))) float tile[TILE];

    // scalar-path weight pointer (addrspace 4 = constant)
    kfloat* wk = (kfloat*)(unsigned long long)wgt;

    // ---- precompute staging slots (ic-invariant, branch-free) ----
    int   goff[LOADS];
    float gmsk[LOADS];
    #pragma unroll
    for (int k = 0; k < LOADS; ++k) {
        int s = threadIdx.x + k*256;
        int lx = s % (TW+2);
        int lt = s / (TW+2);
        int ly = lt % (TH+2);
        int ld = lt / (TH+2);
        int gx = x0 + lx - 1;
        int gy = y0 + ly - 1;
        int gd = d0 + ld - 1;
        bool ok = (s < TILE) && gx >= 0 && gx < W_ && gy >= 0 && gy < H_
                             && gd >= 0 && gd < D_;
        goff[k] = ok ? (gd*HW_ + gy*W_ + gx) : 0;
        gmsk[k] = ok ? 1.f : 0.f;
    }

    float acc[TD][OC];
    #pragma unroll
    for (int od = 0; od < TD; ++od)
        #pragma unroll
        for (int oc = 0; oc < OC; ++oc) acc[od][oc] = bias[oc];

    // prologue: prefetch ic=0 staging values into registers
    float pre[LOADS];
    #pragma unroll
    for (int k = 0; k < LOADS; ++k) pre[k] = in[goff[k]] * gmsk[k];

    for (int ic = 0; ic < IC; ++ic) {
        __syncthreads();               // previous compute done reading tile
        #pragma unroll
        for (int k = 0; k < LOADS; ++k) {
            int s = threadIdx.x + k*256;
            if (s < TILE) tile[s] = pre[k];
        }
        __syncthreads();               // tile ready

        // issue next-ic staging loads NOW; first use is next-iter ds_write,
        // so the latency hides under this iteration's 9-tap FMA phase.
        if (ic + 1 < IC) {
            const float* incn = in + (size_t)(ic + 1) * DHW_;
            #pragma unroll
            for (int k = 0; k < LOADS; ++k) pre[k] = incn[goff[k]] * gmsk[k];
        }

        int lbase = ty*(TW+2) + tx;     // (i=0, j=0) tap address
        int jj = 0;
        #pragma unroll 1
        for (int ij = 0; ij < 9; ++ij) {
            float vals[TD+2];
            #pragma unroll
            for (int p = 0; p < TD+2; ++p)
                vals[p] = tile[p*PLANE + lbase];
            // weights: uniform base (ic,ij) + compile-time (oc,kd) offsets
            // -> s_load s[..], K$-cached, SGPR operand into v_fmac
            kfloat* wp = wk + ic*27 + ij;
            #pragma unroll
            for (int kd = 0; kd < 3; ++kd)
                #pragma unroll
                for (int od = 0; od < TD; ++od) {
                    float v = vals[od + kd];
                    #pragma unroll
                    for (int oc = 0; oc < OC; ++oc)
                        acc[od][oc] = fmaf(wp[oc*IC*27 + kd*9], v, acc[od][oc]);
                }
            // advance tap: j=0,1,2 then next i row
            if (jj == 2) { jj = 0; lbase += (TW+2) - 2; }
            else         { ++jj; ++lbase; }
        }
    }

    #pragma unroll
    for (int od = 0; od < TD; ++od) {
        int obase = (d0 + od)*HW_ + (y0 + ty)*W_ + (x0 + tx);
        #pragma unroll
        for (int oc = 0; oc < OC; ++oc) {
            float r = acc[od][oc];
            if (RELU) r = fmaxf(r, 0.f);
            out[(size_t)oc*DHW_ + obase] = r;
        }
    }
}

// ---------------- softmax over D ------------------------------------------

__global__ __launch_bounds__(256) void softmax_kernel(
        const float* __restrict__ logits, float* __restrict__ out) {
    int pix = blockIdx.x * 256 + threadIdx.x;   // < HW_
    float v[D_];
    float m = -1e30f;
    #pragma unroll
    for (int d = 0; d < D_; ++d) {
        v[d] = logits[d*HW_ + pix];
        m = fmaxf(m, v[d]);
    }
    float s = 0.f;
    #pragma unroll
    for (int d = 0; d < D_; ++d) {
        v[d] = expf(v[d] - m);
        s += v[d];
    }
    float is = 1.f / s;
    #pragma unroll
    for (int d = 0; d < D_; ++d) out[d*HW_ + pix] = v[d] * is;
}

// ---------------- launch ---------------------------------------------------
// ws layout FROZEN (passed rounds 1, 4, 6, 8, 9, 12, 13):
//   proj @ ws+0 (256 B) | var: 32*DHW f32 (126 MB) | hid: 8*DHW f32 (31.5 MB)
// Total 157,286,656 B. Do NOT add ws allocations (round-3 overflow lesson).

extern "C" void kernel_launch(void* const* d_in, const int* in_sizes, int n_in,
                              void* d_out, int out_size, void* d_ws, size_t ws_size,
                              hipStream_t stream) {
    const float* ref_fea = (const float*)d_in[0];
    const float* src1    = (const float*)d_in[1];
    const float* src2    = (const float*)d_in[2];
    const float* ref_prj = (const float*)d_in[3];
    const float* src_pr1 = (const float*)d_in[4];
    const float* src_pr2 = (const float*)d_in[5];
    const float* depth   = (const float*)d_in[6];
    const float* w1      = (const float*)d_in[7];
    const float* b1      = (const float*)d_in[8];
    const float* w2      = (const float*)d_in[9];
    const float* b2      = (const float*)d_in[10];
    float* out = (float*)d_out;

    char* ws = (char*)d_ws;
    float* proj   = (float*)ws;                                         // 24 f
    float* var    = (float*)(ws + 256);                                 // 126 MB
    float* hid    = (float*)(ws + 256 + (size_t)C_*DHW_*sizeof(float)); // 31.5 MB
    float* logits = var;  // variance region dead after conv1 -> reuse

    proj_setup_kernel<<<1, 64, 0, stream>>>(ref_prj, src_pr1, src_pr2, proj);

    variance_kernel<<<DHW_/256, 256, 0, stream>>>(ref_fea, src1, src2, depth, proj, var);

    dim3 cgrid1(W_/32, H_/8, D_/4);  // 5 x 16 x 12 = 960 blocks (3.75 w/SIMD)
    dim3 cgrid2(W_/32, H_/8, D_/8);  // 5 x 16 x 6  = 480 blocks
    conv3d_kernel<32, 8, 4, true ><<<cgrid1, 256, 0, stream>>>(var, w1, b1, hid);
    conv3d_kernel< 8, 1, 8, false><<<cgrid2, 256, 0, stream>>>(hid, w2, b2, logits);

    softmax_kernel<<<HW_/256, 256, 0, stream>>>(logits, out);
}